// Round 12
// baseline (492.069 us; speedup 1.0000x reference)
//
#include <hip/hip_runtime.h>
#include <hip/hip_bf16.h>
#include <math.h>

// GateFusion via bf16 MFMA (16x16x32). Round-9 body + TPW=4 tile loop per
// wave (no prefetch, no per-iter barrier): after the single weight-staging
// barrier, waves free-run across 4 tiles and desynchronize, decorrelating
// stall windows. r5/8/9/11 showed a 2.7-3.0 TB/s ceiling invariant to
// occupancy -- signature of lockstepped one-shot blocks (load burst and
// compute phases coincide across all 8 waves). Register prefetch remains
// banned (r3/4/6/7/11: regalloc sinks or spills it).
// out = g * (x_d@W_d) + (1-g) * (x_c@W_c),
// g = sigmoid( relu(LN(concat@Wg1)) @ Wg2 ),  per row.
//
// d_ws: fragment-linear bf16 weights (see convert_weights):
//   frags 0..19 : Wg1  (ks 0..4) x (nt 0..3)   [K=160, N=64]
//   frags 20..59: [Wd;Wc] (ks 0..4) x (nt 0..7) [K=160, N=128]
// frag = 512 bf16: lane l holds B[k0+j][n], k0=ks*32+(l>>4)*8, n=nt*16+(l&15).

namespace {

typedef __attribute__((ext_vector_type(8))) short short8;
typedef __attribute__((ext_vector_type(4))) float f32x4;

constexpr int CD = 64, CC = 96, CH = 64, CF = 128;
constexpr int NFG1 = 20;   // gate-weight frags (read from L1/L2)
constexpr int NFCB = 40;   // combined-output-weight frags (staged in LDS)
constexpr int NFRAG = NFG1 + NFCB;
constexpr int WCHUNKS = NFCB * 512 * 2 / 16;  // 2560 x 16B = 40960 B
constexpr int TPW = 4;     // 16-row tiles per wave

__device__ inline short bf16_of(float f) {
  __hip_bfloat16 h = __float2bfloat16(f);
  return *reinterpret_cast<short*>(&h);
}

__global__ void convert_weights(const float* __restrict__ Wd,
                                const float* __restrict__ Wc,
                                const float* __restrict__ Wg1,
                                short* __restrict__ ws) {
  const int t = blockIdx.x * 256 + threadIdx.x;
  if (t >= 64 * NFRAG) return;
  const int frag = t >> 6, l = t & 63;
  const int cidx = l & 15, kb = l >> 4;
  float v[8];
  if (frag < NFG1) {
    const int ks = frag >> 2, nt = frag & 3;
    const int n = nt * 16 + cidx, k0 = ks * 32 + kb * 8;
    #pragma unroll
    for (int j = 0; j < 8; ++j) v[j] = Wg1[(k0 + j) * CH + n];
  } else {
    const int f2 = frag - NFG1;
    const int ks = f2 >> 3, nt = f2 & 7;
    const int n = nt * 16 + cidx, k0 = ks * 32 + kb * 8;
    #pragma unroll
    for (int j = 0; j < 8; ++j) {
      const int k = k0 + j;
      v[j] = (k < CD) ? Wd[k * CF + n] : Wc[(k - CD) * CF + n];
    }
  }
  short8 o;
  #pragma unroll
  for (int j = 0; j < 8; ++j) o[j] = bf16_of(v[j]);
  *reinterpret_cast<short8*>(ws + frag * 512 + l * 8) = o;
}

__global__ __launch_bounds__(512, 4)
void gate_fusion_mfma(const float* __restrict__ xd,
                      const float* __restrict__ xc,
                      const float* __restrict__ gma,
                      const float* __restrict__ bta,
                      const float* __restrict__ Wg2,
                      const short* __restrict__ wf,
                      float* __restrict__ out, int nTiles) {
  __shared__ short wlds[NFCB * 512];

  const int tid  = threadIdx.x;
  const int lane = tid & 63;
  const int wv   = tid >> 6;                          // 0..7
  const int tb   = (blockIdx.x * 8 + wv) * TPW;       // first 16-row tile
  const int cidx = lane & 15;
  const int kb   = lane >> 4;
  const int cnt  = (tb < nTiles)
                     ? ((nTiles - tb < TPW) ? (nTiles - tb) : TPW) : 0;

  // ---- stage the 40 output-weight frags (40960 B) into LDS
  {
    const short* wsrc = wf + NFG1 * 512;
    #pragma unroll
    for (int it = 0; it < WCHUNKS / 512; ++it) {
      const int c = tid + it * 512;
      short8 v = *reinterpret_cast<const short8*>(wsrc + (size_t)c * 8);
      *reinterpret_cast<short8*>(&wlds[c * 8]) = v;
    }
  }
  __syncthreads();   // the only barrier; waves free-run afterwards

  // per-wave constants (cache-hit loads)
  float gmv[4], btv[4], w2v[4];
  #pragma unroll
  for (int nt = 0; nt < 4; ++nt) {
    const int c = nt * 16 + cidx;
    gmv[nt] = gma[c]; btv[nt] = bta[c]; w2v[nt] = Wg2[c];
  }

  const f32x4 vzero = {0.f, 0.f, 0.f, 0.f};

  for (int i = 0; i < cnt; ++i) {
    const int r0 = (tb + i) * 16;

    // ---- load this tile's x (10 x 16B per lane)
    f32x4 buf[5][2];
    {
      const size_t row = (size_t)(r0 + cidx);
      const float* rd = xd + row * CD + kb * 8;
      const float* rc = xc + row * CC + kb * 8;
      #pragma unroll
      for (int ks = 0; ks < 5; ++ks) {
        const float* p = (ks < 2) ? (rd + ks * 32) : (rc + (ks - 2) * 32);
        buf[ks][0] = *reinterpret_cast<const f32x4*>(p);
        buf[ks][1] = *reinterpret_cast<const f32x4*>(p + 4);
      }
    }

    // ---- convert x to bf16 A-fragments
    short8 xf[5];
    #pragma unroll
    for (int ks = 0; ks < 5; ++ks) {
      short8 f;
      #pragma unroll
      for (int j = 0; j < 4; ++j) {
        f[j]     = bf16_of(buf[ks][0][j]);
        f[4 + j] = bf16_of(buf[ks][1][j]);
      }
      xf[ks] = f;
    }

    // ---- phase 1: h = x @ Wg1  [16 x 64]  (B-frags from L1/L2)
    f32x4 acc1[4];
    #pragma unroll
    for (int nt = 0; nt < 4; ++nt) acc1[nt] = vzero;

    #pragma unroll
    for (int ks = 0; ks < 5; ++ks) {
      short8 bg[4];
      #pragma unroll
      for (int nt = 0; nt < 4; ++nt)
        bg[nt] = *reinterpret_cast<const short8*>(wf + (ks * 4 + nt) * 512 + lane * 8);
      #pragma unroll
      for (int nt = 0; nt < 4; ++nt)
        acc1[nt] = __builtin_amdgcn_mfma_f32_16x16x32_bf16(
            xf[ks], bg[nt], acc1[nt], 0, 0, 0);
    }

    // ---- LayerNorm + relu + dot(Wg2) + sigmoid (C-fragment layout)
    float gate[4];
    {
      float s[4], q[4];
      #pragma unroll
      for (int r = 0; r < 4; ++r) {
        s[r] = 0.f; q[r] = 0.f;
        #pragma unroll
        for (int nt = 0; nt < 4; ++nt) {
          const float c = acc1[nt][r];
          s[r] += c; q[r] += c * c;
        }
      }
      #pragma unroll
      for (int m = 1; m < 16; m <<= 1)
        #pragma unroll
        for (int r = 0; r < 4; ++r) {
          s[r] += __shfl_xor(s[r], m, 64);
          q[r] += __shfl_xor(q[r], m, 64);
        }
      float p[4];
      #pragma unroll
      for (int r = 0; r < 4; ++r) {
        const float mu  = s[r] * (1.f / CH);
        const float var = q[r] * (1.f / CH) - mu * mu;
        const float rsd = rsqrtf(var + 1e-5f);
        float pp = 0.f;
        #pragma unroll
        for (int nt = 0; nt < 4; ++nt) {
          const float h = fmaxf((acc1[nt][r] - mu) * rsd * gmv[nt] + btv[nt], 0.f);
          pp += h * w2v[nt];
        }
        p[r] = pp;
      }
      #pragma unroll
      for (int m = 1; m < 16; m <<= 1)
        #pragma unroll
        for (int r = 0; r < 4; ++r) p[r] += __shfl_xor(p[r], m, 64);
      #pragma unroll
      for (int r = 0; r < 4; ++r) gate[r] = 1.f / (1.f + expf(-p[r]));
    }

    // ---- phase 2 in 4 nt-quarter slices: dual D/C accumulate, blend, store
    #pragma unroll
    for (int q = 0; q < 4; ++q) {
      f32x4 aD[2], aC[2];
      #pragma unroll
      for (int nt = 0; nt < 2; ++nt) { aD[nt] = vzero; aC[nt] = vzero; }

      #pragma unroll
      for (int ks = 0; ks < 5; ++ks) {
        short8 bg[2];
        #pragma unroll
        for (int nt = 0; nt < 2; ++nt)
          bg[nt] = *reinterpret_cast<const short8*>(
              &wlds[(ks * 8 + q * 2 + nt) * 512 + lane * 8]);
        if (ks < 2) {
          #pragma unroll
          for (int nt = 0; nt < 2; ++nt)
            aD[nt] = __builtin_amdgcn_mfma_f32_16x16x32_bf16(
                xf[ks], bg[nt], aD[nt], 0, 0, 0);
        } else {
          #pragma unroll
          for (int nt = 0; nt < 2; ++nt)
            aC[nt] = __builtin_amdgcn_mfma_f32_16x16x32_bf16(
                xf[ks], bg[nt], aC[nt], 0, 0, 0);
        }
      }

      {
        const size_t rowb = (size_t)r0 + kb * 4;
        #pragma unroll
        for (int nt = 0; nt < 2; ++nt) {
          #pragma unroll
          for (int r = 0; r < 4; ++r) {
            const float g = gate[r];
            const float o = fmaf(g, aD[nt][r] - aC[nt][r], aC[nt][r]);
            out[(rowb + r) * CF + (q * 2 + nt) * 16 + cidx] = o;
          }
        }
      }
    }
  }
}

}  // namespace

extern "C" void kernel_launch(void* const* d_in, const int* in_sizes, int n_in,
                              void* d_out, int out_size, void* d_ws, size_t ws_size,
                              hipStream_t stream) {
  const float* xd  = (const float*)d_in[0];
  const float* xc  = (const float*)d_in[1];
  const float* Wd  = (const float*)d_in[2];
  const float* Wc  = (const float*)d_in[3];
  const float* Wg1 = (const float*)d_in[4];
  const float* gma = (const float*)d_in[5];
  const float* bta = (const float*)d_in[6];
  const float* Wg2 = (const float*)d_in[7];
  float* out = (float*)d_out;
  short* ws  = (short*)d_ws;   // needs 60 KB

  const int N = in_sizes[0] / CD;
  const int nTiles = N / 16;             // N % 16 == 0 -> 31250

  convert_weights<<<dim3(15), dim3(256), 0, stream>>>(Wd, Wc, Wg1, ws);

  const int tilesPerBlock = 8 * TPW;     // 32 tiles per 8-wave block
  const int nblk = (nTiles + tilesPerBlock - 1) / tilesPerBlock;
  gate_fusion_mfma<<<dim3(nblk), dim3(512), 0, stream>>>(
      xd, xc, gma, bta, Wg2, ws, out, nTiles);
}

// Round 13
// 136.127 us; speedup vs baseline: 3.6148x; 3.6148x over previous
//
#include <hip/hip_runtime.h>
#include <hip/hip_bf16.h>
#include <math.h>

// GateFusion via bf16 MFMA (16x16x32). Round-9 one-shot structure (the only
// traffic-exact structure: every per-wave-loop variant r3/4/6/12 inflated
// HBM traffic via compiler hoist/spill) + SINGLE-POINT load-burst pin: one
// asm statement carrying all 10 x-load destinations as "+v" forces all 40
// dest VGPRs simultaneously live -> loads issue back-to-back with ONE exposed
// HBM round-trip (r11's five separate pins let each load sink to its own pin,
// VGPR=36, serialized chain, 2.77 TB/s wall).
// out = g * (x_d@W_d) + (1-g) * (x_c@W_c),
// g = sigmoid( relu(LN(concat@Wg1)) @ Wg2 ),  per row.
//
// d_ws: fragment-linear bf16 weights (see convert_weights):
//   frags 0..19 : Wg1  (ks 0..4) x (nt 0..3)   [K=160, N=64]
//   frags 20..59: [Wd;Wc] (ks 0..4) x (nt 0..7) [K=160, N=128]
// frag = 512 bf16: lane l holds B[k0+j][n], k0=ks*32+(l>>4)*8, n=nt*16+(l&15).

namespace {

typedef __attribute__((ext_vector_type(8))) short short8;
typedef __attribute__((ext_vector_type(4))) float f32x4;

constexpr int CD = 64, CC = 96, CH = 64, CF = 128;
constexpr int NFG1 = 20;   // gate-weight frags (read from L1/L2)
constexpr int NFCB = 40;   // combined-output-weight frags (staged in LDS)
constexpr int NFRAG = NFG1 + NFCB;
constexpr int WCHUNKS = NFCB * 512 * 2 / 16;  // 2560 x 16B = 40960 B

__device__ inline short bf16_of(float f) {
  __hip_bfloat16 h = __float2bfloat16(f);
  return *reinterpret_cast<short*>(&h);
}

__global__ void convert_weights(const float* __restrict__ Wd,
                                const float* __restrict__ Wc,
                                const float* __restrict__ Wg1,
                                short* __restrict__ ws) {
  const int t = blockIdx.x * 256 + threadIdx.x;
  if (t >= 64 * NFRAG) return;
  const int frag = t >> 6, l = t & 63;
  const int cidx = l & 15, kb = l >> 4;
  float v[8];
  if (frag < NFG1) {
    const int ks = frag >> 2, nt = frag & 3;
    const int n = nt * 16 + cidx, k0 = ks * 32 + kb * 8;
    #pragma unroll
    for (int j = 0; j < 8; ++j) v[j] = Wg1[(k0 + j) * CH + n];
  } else {
    const int f2 = frag - NFG1;
    const int ks = f2 >> 3, nt = f2 & 7;
    const int n = nt * 16 + cidx, k0 = ks * 32 + kb * 8;
    #pragma unroll
    for (int j = 0; j < 8; ++j) {
      const int k = k0 + j;
      v[j] = (k < CD) ? Wd[k * CF + n] : Wc[(k - CD) * CF + n];
    }
  }
  short8 o;
  #pragma unroll
  for (int j = 0; j < 8; ++j) o[j] = bf16_of(v[j]);
  *reinterpret_cast<short8*>(ws + frag * 512 + l * 8) = o;
}

__global__ __launch_bounds__(512, 4)
void gate_fusion_mfma(const float* __restrict__ xd,
                      const float* __restrict__ xc,
                      const float* __restrict__ gma,
                      const float* __restrict__ bta,
                      const float* __restrict__ Wg2,
                      const short* __restrict__ wf,
                      float* __restrict__ out, int N) {
  __shared__ short wlds[NFCB * 512];

  const int tid  = threadIdx.x;
  const int lane = tid & 63;
  const int wv   = tid >> 6;                 // 0..7
  const int r0   = blockIdx.x * 128 + wv * 16;   // 16 rows per wave
  const int cidx = lane & 15;
  const int kb   = lane >> 4;
  const bool active = (r0 < N);              // N % 16 == 0: whole-wave granularity

  // ---- issue this wave's x loads first (in flight under staging+barrier)
  f32x4 buf[5][2];
  if (active) {
    const size_t row = (size_t)(r0 + cidx);
    const float* rd = xd + row * CD + kb * 8;
    const float* rc = xc + row * CC + kb * 8;
    #pragma unroll
    for (int ks = 0; ks < 5; ++ks) {
      const float* p = (ks < 2) ? (rd + ks * 32) : (rc + (ks - 2) * 32);
      buf[ks][0] = *reinterpret_cast<const f32x4*>(p);
      buf[ks][1] = *reinterpret_cast<const f32x4*>(p + 4);
    }
  }

  // ---- stage the 40 output-weight frags (40960 B) into LDS
  {
    const short* wsrc = wf + NFG1 * 512;
    #pragma unroll
    for (int it = 0; it < WCHUNKS / 512; ++it) {
      const int c = tid + it * 512;
      short8 v = *reinterpret_cast<const short8*>(wsrc + (size_t)c * 8);
      *reinterpret_cast<short8*>(&wlds[c * 8]) = v;
    }
  }

  // ---- SINGLE pin point: all 10 load destinations live at once -> the 10
  // loads issue as one burst (cannot be sunk/serialized individually).
  if (active) {
    asm volatile(""
        : "+v"(buf[0][0]), "+v"(buf[0][1]), "+v"(buf[1][0]), "+v"(buf[1][1]),
          "+v"(buf[2][0]), "+v"(buf[2][1]), "+v"(buf[3][0]), "+v"(buf[3][1]),
          "+v"(buf[4][0]), "+v"(buf[4][1]));
  }

  __syncthreads();
  if (!active) return;   // after the only barrier

  // per-wave constants (cache-hit loads)
  float gmv[4], btv[4], w2v[4];
  #pragma unroll
  for (int nt = 0; nt < 4; ++nt) {
    const int c = nt * 16 + cidx;
    gmv[nt] = gma[c]; btv[nt] = bta[c]; w2v[nt] = Wg2[c];
  }

  // ---- convert x to bf16 A-fragments
  short8 xf[5];
  #pragma unroll
  for (int ks = 0; ks < 5; ++ks) {
    short8 f;
    #pragma unroll
    for (int j = 0; j < 4; ++j) {
      f[j]     = bf16_of(buf[ks][0][j]);
      f[4 + j] = bf16_of(buf[ks][1][j]);
    }
    xf[ks] = f;
  }

  // ---- phase 1: h = x @ Wg1  [16 x 64]  (B-frags from L1/L2)
  const f32x4 vzero = {0.f, 0.f, 0.f, 0.f};
  f32x4 acc1[4];
  #pragma unroll
  for (int nt = 0; nt < 4; ++nt) acc1[nt] = vzero;

  #pragma unroll
  for (int ks = 0; ks < 5; ++ks) {
    short8 bg[4];
    #pragma unroll
    for (int nt = 0; nt < 4; ++nt)
      bg[nt] = *reinterpret_cast<const short8*>(wf + (ks * 4 + nt) * 512 + lane * 8);
    #pragma unroll
    for (int nt = 0; nt < 4; ++nt)
      acc1[nt] = __builtin_amdgcn_mfma_f32_16x16x32_bf16(
          xf[ks], bg[nt], acc1[nt], 0, 0, 0);
  }

  // ---- LayerNorm + relu + dot(Wg2) + sigmoid (C-fragment layout)
  float gate[4];
  {
    float s[4], q[4];
    #pragma unroll
    for (int r = 0; r < 4; ++r) {
      s[r] = 0.f; q[r] = 0.f;
      #pragma unroll
      for (int nt = 0; nt < 4; ++nt) {
        const float c = acc1[nt][r];
        s[r] += c; q[r] += c * c;
      }
    }
    #pragma unroll
    for (int m = 1; m < 16; m <<= 1)
      #pragma unroll
      for (int r = 0; r < 4; ++r) {
        s[r] += __shfl_xor(s[r], m, 64);
        q[r] += __shfl_xor(q[r], m, 64);
      }
    float p[4];
    #pragma unroll
    for (int r = 0; r < 4; ++r) {
      const float mu  = s[r] * (1.f / CH);
      const float var = q[r] * (1.f / CH) - mu * mu;
      const float rsd = rsqrtf(var + 1e-5f);
      float pp = 0.f;
      #pragma unroll
      for (int nt = 0; nt < 4; ++nt) {
        const float h = fmaxf((acc1[nt][r] - mu) * rsd * gmv[nt] + btv[nt], 0.f);
        pp += h * w2v[nt];
      }
      p[r] = pp;
    }
    #pragma unroll
    for (int m = 1; m < 16; m <<= 1)
      #pragma unroll
      for (int r = 0; r < 4; ++r) p[r] += __shfl_xor(p[r], m, 64);
    #pragma unroll
    for (int r = 0; r < 4; ++r) gate[r] = 1.f / (1.f + expf(-p[r]));
  }

  // ---- phase 2 in 4 nt-quarter slices: dual D/C accumulate, blend, store
  #pragma unroll
  for (int q = 0; q < 4; ++q) {
    f32x4 aD[2], aC[2];
    #pragma unroll
    for (int nt = 0; nt < 2; ++nt) { aD[nt] = vzero; aC[nt] = vzero; }

    #pragma unroll
    for (int ks = 0; ks < 5; ++ks) {
      short8 bg[2];
      #pragma unroll
      for (int nt = 0; nt < 2; ++nt)
        bg[nt] = *reinterpret_cast<const short8*>(
            &wlds[(ks * 8 + q * 2 + nt) * 512 + lane * 8]);
      if (ks < 2) {
        #pragma unroll
        for (int nt = 0; nt < 2; ++nt)
          aD[nt] = __builtin_amdgcn_mfma_f32_16x16x32_bf16(
              xf[ks], bg[nt], aD[nt], 0, 0, 0);
      } else {
        #pragma unroll
        for (int nt = 0; nt < 2; ++nt)
          aC[nt] = __builtin_amdgcn_mfma_f32_16x16x32_bf16(
              xf[ks], bg[nt], aC[nt], 0, 0, 0);
      }
    }

    {
      const size_t rowb = (size_t)r0 + kb * 4;
      #pragma unroll
      for (int nt = 0; nt < 2; ++nt) {
        #pragma unroll
        for (int r = 0; r < 4; ++r) {
          const float g = gate[r];
          const float o = fmaf(g, aD[nt][r] - aC[nt][r], aC[nt][r]);
          out[(rowb + r) * CF + (q * 2 + nt) * 16 + cidx] = o;
        }
      }
    }
  }
}

}  // namespace

extern "C" void kernel_launch(void* const* d_in, const int* in_sizes, int n_in,
                              void* d_out, int out_size, void* d_ws, size_t ws_size,
                              hipStream_t stream) {
  const float* xd  = (const float*)d_in[0];
  const float* xc  = (const float*)d_in[1];
  const float* Wd  = (const float*)d_in[2];
  const float* Wc  = (const float*)d_in[3];
  const float* Wg1 = (const float*)d_in[4];
  const float* gma = (const float*)d_in[5];
  const float* bta = (const float*)d_in[6];
  const float* Wg2 = (const float*)d_in[7];
  float* out = (float*)d_out;
  short* ws  = (short*)d_ws;   // needs 60 KB

  const int N = in_sizes[0] / CD;

  convert_weights<<<dim3(15), dim3(256), 0, stream>>>(Wd, Wc, Wg1, ws);

  const int nblk = (N + 127) / 128;   // 128 rows per 8-wave block
  gate_fusion_mfma<<<dim3(nblk), dim3(512), 0, stream>>>(
      xd, xc, gma, bta, Wg2, ws, out, N);
}